// Round 1
// baseline (469.338 us; speedup 1.0000x reference)
//
#include <hip/hip_runtime.h>
#include <hip/hip_bf16.h>
#include <math.h>

#define NB 2
#define SEQ 1024
#define HDIM 2048
#define NHEADS 16
#define HDHEAD 128
#define PASTN 1024
#define STOT 2048
#define MROWS 2048   // NB*SEQ

typedef __attribute__((ext_vector_type(4))) float f32x4;
typedef __attribute__((ext_vector_type(8))) __bf16 bf16x8;
typedef __attribute__((ext_vector_type(8))) unsigned short us8;
typedef __attribute__((ext_vector_type(4))) unsigned short us4;

__device__ __forceinline__ unsigned short f2bf(float f) {
    union { float f; unsigned int u; } v; v.f = f;
    unsigned int u = v.u;
    u += 0x7FFFu + ((u >> 16) & 1u);
    return (unsigned short)(u >> 16);
}
__device__ __forceinline__ bf16x8 as_bf(us8 u) { return __builtin_bit_cast(bf16x8, u); }

// ---------------- ws layout (bytes) ----------------
#define OFF_COS ((size_t)0)
#define OFF_SIN (OFF_COS + (size_t)SEQ*64*4)
#define OFF_HSB (OFF_SIN + (size_t)SEQ*64*4)
#define OFF_WT  (OFF_HSB + (size_t)MROWS*HDIM*2)
#define OFF_QBF (OFF_WT  + (size_t)4*HDIM*HDIM*2)
#define OFF_KC  (OFF_QBF + (size_t)NB*NHEADS*SEQ*HDHEAD*2)
#define OFF_VT  (OFF_KC  + (size_t)NB*NHEADS*STOT*HDHEAD*2)
#define OFF_ATT (OFF_VT  + (size_t)NB*NHEADS*HDHEAD*STOT*2)

// ---------------- prep kernels ----------------
__global__ void k_rope_table(float* __restrict__ cosT, float* __restrict__ sinT) {
    int idx = blockIdx.x * blockDim.x + threadIdx.x;   // 65536 = 1024*64
    if (idx >= SEQ * 64) return;
    int s = idx >> 6, i = idx & 63;
    float inv = 1.0f / powf(10000.0f, (float)i / 64.0f);
    float a = (float)s * inv;
    cosT[idx] = cosf(a);
    sinT[idx] = sinf(a);
}

__global__ void k_cvt_hidden(const float* __restrict__ in, unsigned short* __restrict__ out) {
    int i = (blockIdx.x * 256 + threadIdx.x) * 4;      // over 4M
    f32x4 v = *(const f32x4*)(in + i);
    us4 o;
    o.x = f2bf(v.x); o.y = f2bf(v.y); o.z = f2bf(v.z); o.w = f2bf(v.w);
    *(us4*)(out + i) = o;
}

// transpose + cvt: W [K][N] fp32 -> WT [N][K] bf16 (z selects Wq/Wk/Wv/Wo)
__global__ void k_wt(const float* __restrict__ Wq, const float* __restrict__ Wk,
                     const float* __restrict__ Wv, const float* __restrict__ Wo,
                     unsigned short* __restrict__ WT) {
    __shared__ unsigned short t[32][33];
    int z = blockIdx.z;
    const float* W = (z == 0) ? Wq : (z == 1) ? Wk : (z == 2) ? Wv : Wo;
    unsigned short* out = WT + (size_t)z * HDIM * HDIM;
    int n0 = blockIdx.x * 32, k0 = blockIdx.y * 32;
    int tx = threadIdx.x, ty = threadIdx.y;  // (32,8)
    #pragma unroll
    for (int j = 0; j < 4; ++j) {
        int kk = ty + j * 8;
        t[kk][tx] = f2bf(W[(size_t)(k0 + kk) * HDIM + n0 + tx]);
    }
    __syncthreads();
    #pragma unroll
    for (int j = 0; j < 4; ++j) {
        int nn = ty + j * 8;
        out[(size_t)(n0 + nn) * HDIM + k0 + tx] = t[tx][nn];
    }
}

// past_key: fp32 copy to d_out k-region + bf16 into Kc (same [bh][p][d] inner layout, ST stride)
__global__ void k_pastk(const float* __restrict__ pk, float* __restrict__ outK,
                        unsigned short* __restrict__ Kc) {
    int i = (blockIdx.x * 256 + threadIdx.x) * 4;      // over 4M
    size_t e = (size_t)i;
    size_t bh = e >> 17;                    // /(1024*128)
    size_t o = e + (bh << 17);              // out has 2048 rows per bh
    f32x4 v = *(const f32x4*)(pk + e);
    *(f32x4*)(outK + o) = v;
    us4 u;
    u.x = f2bf(v.x); u.y = f2bf(v.y); u.z = f2bf(v.z); u.w = f2bf(v.w);
    *(us4*)(Kc + o) = u;
}

// past_value: fp32 copy + transposed bf16 into Vt [bh][d][p]
__global__ void k_pastv(const float* __restrict__ pv, float* __restrict__ outV,
                        unsigned short* __restrict__ Vt) {
    __shared__ unsigned short t[64][65];
    int bh = blockIdx.z;
    int p0 = blockIdx.x * 64, d0 = blockIdx.y * 64;
    int tx = threadIdx.x, ty = threadIdx.y;  // (64,4)
    const float* src = pv + ((size_t)bh * PASTN + p0) * HDHEAD + d0;
    float* dst = outV + ((size_t)bh * STOT + p0) * HDHEAD + d0;
    #pragma unroll
    for (int j = 0; j < 16; ++j) {
        int pp = ty + j * 4;
        float v = src[(size_t)pp * HDHEAD + tx];
        dst[(size_t)pp * HDHEAD + tx] = v;
        t[tx][pp] = f2bf(v);                 // t[d][p]
    }
    __syncthreads();
    unsigned short* vt = Vt + ((size_t)bh * HDHEAD + d0) * STOT + p0;
    #pragma unroll
    for (int j = 0; j < 16; ++j) {
        int dd = ty + j * 4;
        vt[(size_t)dd * STOT + tx] = t[dd][tx];
    }
}

// ---------------- QKV GEMM + bias + RoPE + cache writes ----------------
// C = hsb[2048x2048] @ Wz^T(stored [n][k]) ; tile 128x128, BK=32, 4 waves x (32 rows x 128 cols)
__global__ __launch_bounds__(256) void k_gemm_qkv(
    const unsigned short* __restrict__ hsb, const unsigned short* __restrict__ WT,
    const float* __restrict__ bq, const float* __restrict__ bk, const float* __restrict__ bv,
    const float* __restrict__ cosT, const float* __restrict__ sinT,
    unsigned short* __restrict__ qbf, unsigned short* __restrict__ Kc,
    unsigned short* __restrict__ Vt, float* __restrict__ outK, float* __restrict__ outV) {
    __shared__ __align__(16) unsigned short As[128][40];
    __shared__ __align__(16) unsigned short Bs[128][40];
    const int z = blockIdx.z;
    const unsigned short* Wz = WT + (size_t)z * HDIM * HDIM;
    const float* bias = (z == 0) ? bq : (z == 1) ? bk : bv;
    const int m0 = blockIdx.y * 128;
    const int n0 = blockIdx.x * 128;
    const int h = blockIdx.x;
    const int t = threadIdx.x;
    const int lane = t & 63, w = t >> 6;
    const int c = lane & 15, g = lane >> 4;
    const int srow = t >> 1, scol = (t & 1) * 16;
    const unsigned short* Ag = hsb + (size_t)(m0 + srow) * HDIM + scol;
    const unsigned short* Bg = Wz + (size_t)(n0 + srow) * HDIM + scol;

    f32x4 acc[2][8] = {};
    us8 ra0 = *(const us8*)(Ag);
    us8 ra1 = *(const us8*)(Ag + 8);
    us8 rb0 = *(const us8*)(Bg);
    us8 rb1 = *(const us8*)(Bg + 8);

    for (int k0 = 0; k0 < HDIM; k0 += 32) {
        __syncthreads();
        *(us8*)&As[srow][scol] = ra0;
        *(us8*)&As[srow][scol + 8] = ra1;
        *(us8*)&Bs[srow][scol] = rb0;
        *(us8*)&Bs[srow][scol + 8] = rb1;
        __syncthreads();
        if (k0 + 32 < HDIM) {
            ra0 = *(const us8*)(Ag + k0 + 32);
            ra1 = *(const us8*)(Ag + k0 + 40);
            rb0 = *(const us8*)(Bg + k0 + 32);
            rb1 = *(const us8*)(Bg + k0 + 40);
        }
        const int kk = g * 8;
        bf16x8 af[2];
        #pragma unroll
        for (int mi = 0; mi < 2; ++mi)
            af[mi] = as_bf(*(const us8*)&As[w * 32 + mi * 16 + c][kk]);
        #pragma unroll
        for (int ni = 0; ni < 8; ++ni) {
            bf16x8 bfrag = as_bf(*(const us8*)&Bs[ni * 16 + c][kk]);
            acc[0][ni] = __builtin_amdgcn_mfma_f32_16x16x32_bf16(af[0], bfrag, acc[0][ni], 0, 0, 0);
            acc[1][ni] = __builtin_amdgcn_mfma_f32_16x16x32_bf16(af[1], bfrag, acc[1][ni], 0, 0, 0);
        }
    }

    const float invsq = 0.08838834764831845f;  // 1/sqrt(128)
    #pragma unroll
    for (int mi = 0; mi < 2; ++mi) {
        #pragma unroll
        for (int r = 0; r < 4; ++r) {
            const int row = m0 + w * 32 + mi * 16 + g * 4 + r;
            const int b = row >> 10, s = row & 1023;
            const size_t bh = (size_t)(b * NHEADS + h);
            #pragma unroll
            for (int ni = 0; ni < 8; ++ni) {
                const int d = ni * 16 + c;
                const float val = acc[mi][ni][r] + bias[n0 + d];
                if (z == 2) {
                    const size_t vo = (bh * STOT + PASTN + s) * HDHEAD + d;
                    outV[vo] = val;
                    Vt[(bh * HDHEAD + d) * STOT + PASTN + s] = f2bf(val);
                } else {
                    const int fidx = d & 63;
                    const float cv = cosT[s * 64 + fidx];
                    const float sv = sinT[s * 64 + fidx];
                    const float other = acc[mi][ni ^ 4][r] + bias[n0 + (d ^ 64)];
                    const float rot = (d < 64) ? (val * cv - other * sv)
                                               : (val * cv + other * sv);
                    if (z == 0) {
                        qbf[(bh * SEQ + s) * HDHEAD + d] = f2bf(rot * invsq);
                    } else {
                        const size_t ko = (bh * STOT + PASTN + s) * HDHEAD + d;
                        Kc[ko] = f2bf(rot);
                        outK[ko] = rot;
                    }
                }
            }
        }
    }
}

// ---------------- flash attention ----------------
// grid (16 qtiles, 32 bh), 4 waves x 16 q-rows each; key tiles of 64
__global__ __launch_bounds__(256) void k_attn(
    const unsigned short* __restrict__ qbf, const unsigned short* __restrict__ Kc,
    const unsigned short* __restrict__ Vt, unsigned short* __restrict__ attn) {
    __shared__ __align__(16) unsigned short P[4][16][72];
    const int qt = blockIdx.x;
    const int bh = blockIdx.y;
    const int b = bh >> 4, h = bh & 15;
    const int t = threadIdx.x, lane = t & 63, w = t >> 6;
    const int c = lane & 15, g = lane >> 4;
    const int q0 = qt * 64 + w * 16;
    const unsigned short* Qb = qbf + ((size_t)bh * SEQ + q0) * HDHEAD;
    const unsigned short* Kb = Kc + (size_t)bh * STOT * HDHEAD;
    const unsigned short* Vb = Vt + (size_t)bh * HDHEAD * STOT;

    bf16x8 qf[4];
    #pragma unroll
    for (int kf = 0; kf < 4; ++kf)
        qf[kf] = as_bf(*(const us8*)(Qb + (size_t)c * HDHEAD + kf * 32 + g * 8));

    f32x4 o[8] = {};
    float mrow[4] = {-1e30f, -1e30f, -1e30f, -1e30f};
    float lrow[4] = {0.f, 0.f, 0.f, 0.f};
    const int nkt = 17 + qt;
    for (int kt = 0; kt < nkt; ++kt) {
        const int k0 = kt * 64;
        f32x4 sa[4] = {};
        #pragma unroll
        for (int nf = 0; nf < 4; ++nf) {
            #pragma unroll
            for (int kf = 0; kf < 4; ++kf) {
                bf16x8 kf8 = as_bf(*(const us8*)(Kb + (size_t)(k0 + nf * 16 + c) * HDHEAD + kf * 32 + g * 8));
                sa[nf] = __builtin_amdgcn_mfma_f32_16x16x32_bf16(qf[kf], kf8, sa[nf], 0, 0, 0);
            }
        }
        if (k0 + 63 > PASTN + q0) {
            #pragma unroll
            for (int nf = 0; nf < 4; ++nf) {
                const int j = k0 + nf * 16 + c;
                #pragma unroll
                for (int r = 0; r < 4; ++r)
                    if (j > PASTN + q0 + g * 4 + r) sa[nf][r] = -1e30f;
            }
        }
        #pragma unroll
        for (int r = 0; r < 4; ++r) {
            float mx = fmaxf(fmaxf(sa[0][r], sa[1][r]), fmaxf(sa[2][r], sa[3][r]));
            mx = fmaxf(mx, __shfl_xor(mx, 1));
            mx = fmaxf(mx, __shfl_xor(mx, 2));
            mx = fmaxf(mx, __shfl_xor(mx, 4));
            mx = fmaxf(mx, __shfl_xor(mx, 8));
            const float mnew = fmaxf(mrow[r], mx);
            const float alpha = __expf(mrow[r] - mnew);
            mrow[r] = mnew;
            float ps = 0.f;
            #pragma unroll
            for (int nf = 0; nf < 4; ++nf) {
                const float p = __expf(sa[nf][r] - mnew);
                sa[nf][r] = p;
                ps += p;
            }
            ps += __shfl_xor(ps, 1);
            ps += __shfl_xor(ps, 2);
            ps += __shfl_xor(ps, 4);
            ps += __shfl_xor(ps, 8);
            lrow[r] = lrow[r] * alpha + ps;
            #pragma unroll
            for (int nd = 0; nd < 8; ++nd) o[nd][r] *= alpha;
        }
        __syncthreads();
        #pragma unroll
        for (int nf = 0; nf < 4; ++nf)
            #pragma unroll
            for (int r = 0; r < 4; ++r)
                P[w][g * 4 + r][nf * 16 + c] = f2bf(sa[nf][r]);
        __syncthreads();
        #pragma unroll
        for (int kf2 = 0; kf2 < 2; ++kf2) {
            const bf16x8 pa = as_bf(*(const us8*)&P[w][c][kf2 * 32 + g * 8]);
            #pragma unroll
            for (int nd = 0; nd < 8; ++nd) {
                const bf16x8 vf = as_bf(*(const us8*)(Vb + (size_t)(nd * 16 + c) * STOT + k0 + kf2 * 32 + g * 8));
                o[nd] = __builtin_amdgcn_mfma_f32_16x16x32_bf16(pa, vf, o[nd], 0, 0, 0);
            }
        }
    }
    #pragma unroll
    for (int r = 0; r < 4; ++r) {
        const float inv = 1.0f / lrow[r];
        #pragma unroll
        for (int nd = 0; nd < 8; ++nd) o[nd][r] *= inv;
    }
    #pragma unroll
    for (int nd = 0; nd < 8; ++nd)
        #pragma unroll
        for (int r = 0; r < 4; ++r) {
            const int srow = q0 + g * 4 + r;
            attn[((size_t)b * SEQ + srow) * HDIM + h * HDHEAD + nd * 16 + c] = f2bf(o[nd][r]);
        }
}

// ---------------- output projection ----------------
__global__ __launch_bounds__(256) void k_gemm_out(
    const unsigned short* __restrict__ attn, const unsigned short* __restrict__ WTo,
    const float* __restrict__ bo, float* __restrict__ out) {
    __shared__ __align__(16) unsigned short As[128][40];
    __shared__ __align__(16) unsigned short Bs[128][40];
    const int m0 = blockIdx.y * 128;
    const int n0 = blockIdx.x * 128;
    const int t = threadIdx.x;
    const int lane = t & 63, w = t >> 6;
    const int c = lane & 15, g = lane >> 4;
    const int srow = t >> 1, scol = (t & 1) * 16;
    const unsigned short* Ag = attn + (size_t)(m0 + srow) * HDIM + scol;
    const unsigned short* Bg = WTo + (size_t)(n0 + srow) * HDIM + scol;

    f32x4 acc[2][8] = {};
    us8 ra0 = *(const us8*)(Ag);
    us8 ra1 = *(const us8*)(Ag + 8);
    us8 rb0 = *(const us8*)(Bg);
    us8 rb1 = *(const us8*)(Bg + 8);

    for (int k0 = 0; k0 < HDIM; k0 += 32) {
        __syncthreads();
        *(us8*)&As[srow][scol] = ra0;
        *(us8*)&As[srow][scol + 8] = ra1;
        *(us8*)&Bs[srow][scol] = rb0;
        *(us8*)&Bs[srow][scol + 8] = rb1;
        __syncthreads();
        if (k0 + 32 < HDIM) {
            ra0 = *(const us8*)(Ag + k0 + 32);
            ra1 = *(const us8*)(Ag + k0 + 40);
            rb0 = *(const us8*)(Bg + k0 + 32);
            rb1 = *(const us8*)(Bg + k0 + 40);
        }
        const int kk = g * 8;
        bf16x8 af[2];
        #pragma unroll
        for (int mi = 0; mi < 2; ++mi)
            af[mi] = as_bf(*(const us8*)&As[w * 32 + mi * 16 + c][kk]);
        #pragma unroll
        for (int ni = 0; ni < 8; ++ni) {
            bf16x8 bfrag = as_bf(*(const us8*)&Bs[ni * 16 + c][kk]);
            acc[0][ni] = __builtin_amdgcn_mfma_f32_16x16x32_bf16(af[0], bfrag, acc[0][ni], 0, 0, 0);
            acc[1][ni] = __builtin_amdgcn_mfma_f32_16x16x32_bf16(af[1], bfrag, acc[1][ni], 0, 0, 0);
        }
    }
    #pragma unroll
    for (int mi = 0; mi < 2; ++mi)
        #pragma unroll
        for (int r = 0; r < 4; ++r) {
            const int row = m0 + w * 32 + mi * 16 + g * 4 + r;
            #pragma unroll
            for (int ni = 0; ni < 8; ++ni) {
                const int f = n0 + ni * 16 + c;
                out[(size_t)row * HDIM + f] = acc[mi][ni][r] + bo[f];
            }
        }
}

extern "C" void kernel_launch(void* const* d_in, const int* in_sizes, int n_in,
                              void* d_out, int out_size, void* d_ws, size_t ws_size,
                              hipStream_t stream) {
    const float* hidden = (const float*)d_in[0];
    // d_in[1] = mask (causality computed analytically)
    const float* past_key = (const float*)d_in[2];
    const float* past_value = (const float*)d_in[3];
    const float* Wq = (const float*)d_in[4];
    const float* bq = (const float*)d_in[5];
    const float* Wk = (const float*)d_in[6];
    const float* bk = (const float*)d_in[7];
    const float* Wv = (const float*)d_in[8];
    const float* bv = (const float*)d_in[9];
    const float* Wo = (const float*)d_in[10];
    const float* bo = (const float*)d_in[11];

    float* out0 = (float*)d_out;
    float* outK = out0 + (size_t)NB * SEQ * HDIM;
    float* outV = outK + (size_t)NB * NHEADS * STOT * HDHEAD;

    char* ws = (char*)d_ws;
    float* cosT = (float*)(ws + OFF_COS);
    float* sinT = (float*)(ws + OFF_SIN);
    unsigned short* hsb = (unsigned short*)(ws + OFF_HSB);
    unsigned short* WT = (unsigned short*)(ws + OFF_WT);
    unsigned short* qbf = (unsigned short*)(ws + OFF_QBF);
    unsigned short* Kc = (unsigned short*)(ws + OFF_KC);
    unsigned short* Vt = (unsigned short*)(ws + OFF_VT);
    unsigned short* attnb = (unsigned short*)(ws + OFF_ATT);

    k_rope_table<<<dim3(256), dim3(256), 0, stream>>>(cosT, sinT);
    k_cvt_hidden<<<dim3(4096), dim3(256), 0, stream>>>(hidden, hsb);
    k_wt<<<dim3(64, 64, 4), dim3(32, 8), 0, stream>>>(Wq, Wk, Wv, Wo, WT);
    k_pastk<<<dim3(4096), dim3(256), 0, stream>>>(past_key, outK, Kc);
    k_pastv<<<dim3(16, 2, 32), dim3(64, 4), 0, stream>>>(past_value, outV, Vt);
    k_gemm_qkv<<<dim3(16, 16, 3), dim3(256), 0, stream>>>(
        hsb, WT, bq, bk, bv, cosT, sinT, qbf, Kc, Vt, outK, outV);
    k_attn<<<dim3(16, 32), dim3(256), 0, stream>>>(qbf, Kc, Vt, attnb);
    k_gemm_out<<<dim3(16, 16), dim3(256), 0, stream>>>(
        attnb, WT + (size_t)3 * HDIM * HDIM, bo, out0);
}

// Round 2
// 277.052 us; speedup vs baseline: 1.6940x; 1.6940x over previous
//
#include <hip/hip_runtime.h>
#include <hip/hip_bf16.h>
#include <math.h>

#define NB 2
#define SEQ 1024
#define HDIM 2048
#define NHEADS 16
#define HDHEAD 128
#define PASTN 1024
#define STOT 2048
#define MROWS 2048   // NB*SEQ

typedef __attribute__((ext_vector_type(4))) float f32x4;
typedef __attribute__((ext_vector_type(8))) __bf16 bf16x8;
typedef __attribute__((ext_vector_type(8))) unsigned short us8;
typedef __attribute__((ext_vector_type(4))) unsigned short us4;

__device__ __forceinline__ unsigned short f2bf(float f) {
    union { float f; unsigned int u; } v; v.f = f;
    unsigned int u = v.u;
    u += 0x7FFFu + ((u >> 16) & 1u);
    return (unsigned short)(u >> 16);
}
__device__ __forceinline__ bf16x8 as_bf(us8 u) { return __builtin_bit_cast(bf16x8, u); }

// async global->LDS, 16B per lane; LDS dest is wave-uniform base + lane*16
__device__ __forceinline__ void gl16(const unsigned short* g, unsigned short* l) {
    __builtin_amdgcn_global_load_lds(
        (const __attribute__((address_space(1))) void*)g,
        (__attribute__((address_space(3))) void*)l, 16, 0, 0);
}

// ---------------- ws layout (bytes) ----------------
#define OFF_COS ((size_t)0)
#define OFF_SIN (OFF_COS + (size_t)SEQ*64*4)
#define OFF_HSB (OFF_SIN + (size_t)SEQ*64*4)
#define OFF_WT  (OFF_HSB + (size_t)MROWS*HDIM*2)
#define OFF_QBF (OFF_WT  + (size_t)4*HDIM*HDIM*2)
#define OFF_KC  (OFF_QBF + (size_t)NB*NHEADS*SEQ*HDHEAD*2)
#define OFF_VT  (OFF_KC  + (size_t)NB*NHEADS*STOT*HDHEAD*2)
#define OFF_ATT (OFF_VT  + (size_t)NB*NHEADS*HDHEAD*STOT*2)

// K cache tiled layout: Kc2[(bh*32+kt)*8192 + pr*128 + (d ^ ((p&7)<<3))], pr=p&63
// V cache tiled layout: Vt2[(bh*32+kt)*8192 + d*64 + ((p&63) ^ ((d&7)<<3))]

// ---------------- prep kernels ----------------
__global__ void k_rope_table(float* __restrict__ cosT, float* __restrict__ sinT) {
    int idx = blockIdx.x * blockDim.x + threadIdx.x;   // 65536 = 1024*64
    if (idx >= SEQ * 64) return;
    int s = idx >> 6, i = idx & 63;
    float inv = 1.0f / powf(10000.0f, (float)i / 64.0f);
    float a = (float)s * inv;
    cosT[idx] = cosf(a);
    sinT[idx] = sinf(a);
}

__global__ void k_cvt_hidden(const float* __restrict__ in, unsigned short* __restrict__ out) {
    int i = (blockIdx.x * 256 + threadIdx.x) * 4;      // over 4M
    f32x4 v = *(const f32x4*)(in + i);
    us4 o;
    o.x = f2bf(v.x); o.y = f2bf(v.y); o.z = f2bf(v.z); o.w = f2bf(v.w);
    *(us4*)(out + i) = o;
}

// transpose + cvt: W [K][N] fp32 -> WT [N][K] bf16 (z selects Wq/Wk/Wv/Wo)
__global__ void k_wt(const float* __restrict__ Wq, const float* __restrict__ Wk,
                     const float* __restrict__ Wv, const float* __restrict__ Wo,
                     unsigned short* __restrict__ WT) {
    __shared__ unsigned short t[32][33];
    int z = blockIdx.z;
    const float* W = (z == 0) ? Wq : (z == 1) ? Wk : (z == 2) ? Wv : Wo;
    unsigned short* out = WT + (size_t)z * HDIM * HDIM;
    int n0 = blockIdx.x * 32, k0 = blockIdx.y * 32;
    int tx = threadIdx.x, ty = threadIdx.y;  // (32,8)
    #pragma unroll
    for (int j = 0; j < 4; ++j) {
        int kk = ty + j * 8;
        t[kk][tx] = f2bf(W[(size_t)(k0 + kk) * HDIM + n0 + tx]);
    }
    __syncthreads();
    #pragma unroll
    for (int j = 0; j < 4; ++j) {
        int nn = ty + j * 8;
        out[(size_t)(n0 + nn) * HDIM + k0 + tx] = t[tx][nn];
    }
}

// past_key: fp32 copy to d_out k-region + bf16 into tiled/swizzled Kc2
__global__ void k_pastk(const float* __restrict__ pk, float* __restrict__ outK,
                        unsigned short* __restrict__ Kc2) {
    int i = (blockIdx.x * 256 + threadIdx.x) * 4;      // over 4M
    size_t e = (size_t)i;
    size_t bh = e >> 17;                    // /(1024*128)
    int p = (int)((e >> 7) & 1023);
    int d0 = (int)(e & 127);                // 4-aligned
    f32x4 v = *(const f32x4*)(pk + e);
    size_t o = e + (bh << 17);              // outK has 2048 rows per bh
    *(f32x4*)(outK + o) = v;
    us4 u;
    u.x = f2bf(v.x); u.y = f2bf(v.y); u.z = f2bf(v.z); u.w = f2bf(v.w);
    const int kt = p >> 6, pr = p & 63;
    const size_t idx = ((bh * 32 + kt) << 13) + (size_t)pr * 128 + (d0 ^ ((p & 7) << 3));
    *(us4*)(Kc2 + idx) = u;
}

// past_value: fp32 copy + tiled/swizzled bf16 into Vt2
__global__ void k_pastv(const float* __restrict__ pv, float* __restrict__ outV,
                        unsigned short* __restrict__ Vt2) {
    __shared__ unsigned short t[64][65];
    int bh = blockIdx.z;
    int p0 = blockIdx.x * 64, d0 = blockIdx.y * 64;
    int tx = threadIdx.x, ty = threadIdx.y;  // (64,4)
    const float* src = pv + ((size_t)bh * PASTN + p0) * HDHEAD + d0;
    float* dst = outV + ((size_t)bh * STOT + p0) * HDHEAD + d0;
    #pragma unroll
    for (int j = 0; j < 16; ++j) {
        int pp = ty + j * 4;
        float v = src[(size_t)pp * HDHEAD + tx];
        dst[(size_t)pp * HDHEAD + tx] = v;
        t[tx][pp] = f2bf(v);                 // t[d_off][p_off]
    }
    __syncthreads();
    unsigned short* vt = Vt2 + (((size_t)bh * 32 + (p0 >> 6)) << 13);
    #pragma unroll
    for (int j = 0; j < 16; ++j) {
        int dd = ty + j * 4;
        const int d = d0 + dd;
        vt[(size_t)d * 64 + (tx ^ ((d & 7) << 3))] = t[dd][tx];
    }
}

// ---------------- QKV GEMM + bias + RoPE + cache writes ----------------
__global__ __launch_bounds__(256) void k_gemm_qkv(
    const unsigned short* __restrict__ hsb, const unsigned short* __restrict__ WT,
    const float* __restrict__ bq, const float* __restrict__ bk, const float* __restrict__ bv,
    const float* __restrict__ cosT, const float* __restrict__ sinT,
    unsigned short* __restrict__ qbf, unsigned short* __restrict__ Kc2,
    unsigned short* __restrict__ Vt2, float* __restrict__ outK, float* __restrict__ outV) {
    __shared__ __align__(16) unsigned short As[128][40];
    __shared__ __align__(16) unsigned short Bs[128][40];
    const int z = blockIdx.z;
    const unsigned short* Wz = WT + (size_t)z * HDIM * HDIM;
    const float* bias = (z == 0) ? bq : (z == 1) ? bk : bv;
    const int m0 = blockIdx.y * 128;
    const int n0 = blockIdx.x * 128;
    const int h = blockIdx.x;
    const int t = threadIdx.x;
    const int lane = t & 63, w = t >> 6;
    const int c = lane & 15, g = lane >> 4;
    const int srow = t >> 1, scol = (t & 1) * 16;
    const unsigned short* Ag = hsb + (size_t)(m0 + srow) * HDIM + scol;
    const unsigned short* Bg = Wz + (size_t)(n0 + srow) * HDIM + scol;

    f32x4 acc[2][8] = {};
    us8 ra0 = *(const us8*)(Ag);
    us8 ra1 = *(const us8*)(Ag + 8);
    us8 rb0 = *(const us8*)(Bg);
    us8 rb1 = *(const us8*)(Bg + 8);

    for (int k0 = 0; k0 < HDIM; k0 += 32) {
        __syncthreads();
        *(us8*)&As[srow][scol] = ra0;
        *(us8*)&As[srow][scol + 8] = ra1;
        *(us8*)&Bs[srow][scol] = rb0;
        *(us8*)&Bs[srow][scol + 8] = rb1;
        __syncthreads();
        if (k0 + 32 < HDIM) {
            ra0 = *(const us8*)(Ag + k0 + 32);
            ra1 = *(const us8*)(Ag + k0 + 40);
            rb0 = *(const us8*)(Bg + k0 + 32);
            rb1 = *(const us8*)(Bg + k0 + 40);
        }
        const int kk = g * 8;
        bf16x8 af[2];
        #pragma unroll
        for (int mi = 0; mi < 2; ++mi)
            af[mi] = as_bf(*(const us8*)&As[w * 32 + mi * 16 + c][kk]);
        #pragma unroll
        for (int ni = 0; ni < 8; ++ni) {
            bf16x8 bfrag = as_bf(*(const us8*)&Bs[ni * 16 + c][kk]);
            acc[0][ni] = __builtin_amdgcn_mfma_f32_16x16x32_bf16(af[0], bfrag, acc[0][ni], 0, 0, 0);
            acc[1][ni] = __builtin_amdgcn_mfma_f32_16x16x32_bf16(af[1], bfrag, acc[1][ni], 0, 0, 0);
        }
    }

    const float invsq = 0.08838834764831845f;  // 1/sqrt(128)
    #pragma unroll
    for (int mi = 0; mi < 2; ++mi) {
        #pragma unroll
        for (int r = 0; r < 4; ++r) {
            const int row = m0 + w * 32 + mi * 16 + g * 4 + r;
            const int b = row >> 10, s = row & 1023;
            const size_t bh = (size_t)(b * NHEADS + h);
            const int p = PASTN + s;
            #pragma unroll
            for (int ni = 0; ni < 8; ++ni) {
                const int d = ni * 16 + c;
                const float val = acc[mi][ni][r] + bias[n0 + d];
                if (z == 2) {
                    outV[(bh * STOT + p) * HDHEAD + d] = val;
                    Vt2[((bh * 32 + (p >> 6)) << 13) + (size_t)d * 64 +
                        ((p & 63) ^ ((d & 7) << 3))] = f2bf(val);
                } else {
                    const int fidx = d & 63;
                    const float cv = cosT[s * 64 + fidx];
                    const float sv = sinT[s * 64 + fidx];
                    const float other = acc[mi][ni ^ 4][r] + bias[n0 + (d ^ 64)];
                    const float rot = (d < 64) ? (val * cv - other * sv)
                                               : (val * cv + other * sv);
                    if (z == 0) {
                        qbf[(bh * SEQ + s) * HDHEAD + d] = f2bf(rot * invsq);
                    } else {
                        Kc2[((bh * 32 + (p >> 6)) << 13) + (size_t)(p & 63) * 128 +
                            (d ^ ((p & 7) << 3))] = f2bf(rot);
                        outK[(bh * STOT + p) * HDHEAD + d] = rot;
                    }
                }
            }
        }
    }
}

// ---------------- flash attention, LDS-staged + prefetched ----------------
// grid (16 qtiles, 32 bh), 4 waves x 16 q-rows; key tiles of 64
// K double-buffered (2x16KB), V single-buffered (16KB), counted vmcnt + raw barriers
__global__ __launch_bounds__(256) void k_attn(
    const unsigned short* __restrict__ qbf, const unsigned short* __restrict__ Kc2,
    const unsigned short* __restrict__ Vt2, unsigned short* __restrict__ attn) {
    __shared__ __align__(16) unsigned short Ks[2][64 * 128];
    __shared__ __align__(16) unsigned short Vs[128 * 64];
    __shared__ __align__(16) unsigned short P[4][16][72];
    const int qt = blockIdx.x;
    const int bh = blockIdx.y;
    const int b = bh >> 4, h = bh & 15;
    const int t = threadIdx.x, lane = t & 63, w = t >> 6;
    const int c = lane & 15, g = lane >> 4;
    const int q0 = qt * 64 + w * 16;
    const unsigned short* Qb = qbf + ((size_t)bh * SEQ + q0) * HDHEAD;
    const unsigned short* Kbase = Kc2 + ((size_t)bh << 18);   // *32*8192
    const unsigned short* Vbase = Vt2 + ((size_t)bh << 18);

    bf16x8 qf[4];
    #pragma unroll
    for (int kf = 0; kf < 4; ++kf)
        qf[kf] = as_bf(*(const us8*)(Qb + (size_t)c * HDHEAD + kf * 32 + g * 8));

    // prologue: stage K tile 0
    #pragma unroll
    for (int j = 0; j < 4; ++j) {
        const int ch = w * 4 + j;
        gl16(Kbase + ch * 512 + lane * 8, &Ks[0][ch * 512]);
    }

    f32x4 o[8] = {};
    float mrow[4] = {-1e30f, -1e30f, -1e30f, -1e30f};
    float lrow[4] = {0.f, 0.f, 0.f, 0.f};
    const int nkt = 17 + qt;
    int cur = 0;
    for (int kt = 0; kt < nkt; ++kt) {
        // (A) K(kt) landed; Vs free (all waves past PV of kt-1)
        asm volatile("s_waitcnt vmcnt(0)" ::: "memory");
        __builtin_amdgcn_s_barrier();
        // issue V(kt), then K(kt+1) into the other K buffer
        const unsigned short* Vg = Vbase + ((size_t)kt << 13);
        #pragma unroll
        for (int j = 0; j < 4; ++j) {
            const int ch = w * 4 + j;
            gl16(Vg + ch * 512 + lane * 8, &Vs[ch * 512]);
        }
        if (kt + 1 < nkt) {
            const unsigned short* Kg = Kbase + ((size_t)(kt + 1) << 13);
            #pragma unroll
            for (int j = 0; j < 4; ++j) {
                const int ch = w * 4 + j;
                gl16(Kg + ch * 512 + lane * 8, &Ks[cur ^ 1][ch * 512]);
            }
        }
        // QK^T from Ks[cur] (swizzled reads)
        f32x4 sa[4] = {};
        #pragma unroll
        for (int nf = 0; nf < 4; ++nf) {
            const int row = nf * 16 + c;
            const int swz = (row & 7) << 3;
            #pragma unroll
            for (int kf = 0; kf < 4; ++kf) {
                bf16x8 kf8 = as_bf(*(const us8*)&Ks[cur][row * 128 + ((kf * 32 + g * 8) ^ swz)]);
                sa[nf] = __builtin_amdgcn_mfma_f32_16x16x32_bf16(qf[kf], kf8, sa[nf], 0, 0, 0);
            }
        }
        const int k0 = kt * 64;
        if (k0 + 63 > PASTN + q0) {
            #pragma unroll
            for (int nf = 0; nf < 4; ++nf) {
                const int j = k0 + nf * 16 + c;
                #pragma unroll
                for (int r = 0; r < 4; ++r)
                    if (j > PASTN + q0 + g * 4 + r) sa[nf][r] = -1e30f;
            }
        }
        #pragma unroll
        for (int r = 0; r < 4; ++r) {
            float mx = fmaxf(fmaxf(sa[0][r], sa[1][r]), fmaxf(sa[2][r], sa[3][r]));
            mx = fmaxf(mx, __shfl_xor(mx, 1));
            mx = fmaxf(mx, __shfl_xor(mx, 2));
            mx = fmaxf(mx, __shfl_xor(mx, 4));
            mx = fmaxf(mx, __shfl_xor(mx, 8));
            const float mnew = fmaxf(mrow[r], mx);
            const float alpha = __expf(mrow[r] - mnew);
            mrow[r] = mnew;
            float ps = 0.f;
            #pragma unroll
            for (int nf = 0; nf < 4; ++nf) {
                const float p = __expf(sa[nf][r] - mnew);
                sa[nf][r] = p;
                ps += p;
            }
            ps += __shfl_xor(ps, 1);
            ps += __shfl_xor(ps, 2);
            ps += __shfl_xor(ps, 4);
            ps += __shfl_xor(ps, 8);
            lrow[r] = lrow[r] * alpha + ps;
            #pragma unroll
            for (int nd = 0; nd < 8; ++nd) o[nd][r] *= alpha;
        }
        // (B) V(kt) landed (this wave's 4 oldest loads); K(kt+1) stays in flight
        if (kt + 1 < nkt) {
            asm volatile("s_waitcnt vmcnt(4)" ::: "memory");
        } else {
            asm volatile("s_waitcnt vmcnt(0)" ::: "memory");
        }
        __builtin_amdgcn_s_barrier();
        // P round-trip is wave-private: no block barrier needed
        #pragma unroll
        for (int nf = 0; nf < 4; ++nf)
            #pragma unroll
            for (int r = 0; r < 4; ++r)
                P[w][g * 4 + r][nf * 16 + c] = f2bf(sa[nf][r]);
        #pragma unroll
        for (int kf2 = 0; kf2 < 2; ++kf2) {
            const bf16x8 pa = as_bf(*(const us8*)&P[w][c][kf2 * 32 + g * 8]);
            #pragma unroll
            for (int nd = 0; nd < 8; ++nd) {
                const int d = nd * 16 + c;
                const bf16x8 vf = as_bf(*(const us8*)&Vs[d * 64 + ((kf2 * 32 + g * 8) ^ ((d & 7) << 3))]);
                o[nd] = __builtin_amdgcn_mfma_f32_16x16x32_bf16(pa, vf, o[nd], 0, 0, 0);
            }
        }
        cur ^= 1;
    }
    #pragma unroll
    for (int r = 0; r < 4; ++r) {
        const float inv = 1.0f / lrow[r];
        #pragma unroll
        for (int nd = 0; nd < 8; ++nd) o[nd][r] *= inv;
    }
    #pragma unroll
    for (int nd = 0; nd < 8; ++nd)
        #pragma unroll
        for (int r = 0; r < 4; ++r) {
            const int srow = q0 + g * 4 + r;
            attn[((size_t)b * SEQ + srow) * HDIM + h * HDHEAD + nd * 16 + c] = f2bf(o[nd][r]);
        }
}

// ---------------- output projection ----------------
__global__ __launch_bounds__(256) void k_gemm_out(
    const unsigned short* __restrict__ attn, const unsigned short* __restrict__ WTo,
    const float* __restrict__ bo, float* __restrict__ out) {
    __shared__ __align__(16) unsigned short As[128][40];
    __shared__ __align__(16) unsigned short Bs[128][40];
    const int m0 = blockIdx.y * 128;
    const int n0 = blockIdx.x * 128;
    const int t = threadIdx.x;
    const int lane = t & 63, w = t >> 6;
    const int c = lane & 15, g = lane >> 4;
    const int srow = t >> 1, scol = (t & 1) * 16;
    const unsigned short* Ag = attn + (size_t)(m0 + srow) * HDIM + scol;
    const unsigned short* Bg = WTo + (size_t)(n0 + srow) * HDIM + scol;

    f32x4 acc[2][8] = {};
    us8 ra0 = *(const us8*)(Ag);
    us8 ra1 = *(const us8*)(Ag + 8);
    us8 rb0 = *(const us8*)(Bg);
    us8 rb1 = *(const us8*)(Bg + 8);

    for (int k0 = 0; k0 < HDIM; k0 += 32) {
        __syncthreads();
        *(us8*)&As[srow][scol] = ra0;
        *(us8*)&As[srow][scol + 8] = ra1;
        *(us8*)&Bs[srow][scol] = rb0;
        *(us8*)&Bs[srow][scol + 8] = rb1;
        __syncthreads();
        if (k0 + 32 < HDIM) {
            ra0 = *(const us8*)(Ag + k0 + 32);
            ra1 = *(const us8*)(Ag + k0 + 40);
            rb0 = *(const us8*)(Bg + k0 + 32);
            rb1 = *(const us8*)(Bg + k0 + 40);
        }
        const int kk = g * 8;
        bf16x8 af[2];
        #pragma unroll
        for (int mi = 0; mi < 2; ++mi)
            af[mi] = as_bf(*(const us8*)&As[w * 32 + mi * 16 + c][kk]);
        #pragma unroll
        for (int ni = 0; ni < 8; ++ni) {
            bf16x8 bfrag = as_bf(*(const us8*)&Bs[ni * 16 + c][kk]);
            acc[0][ni] = __builtin_amdgcn_mfma_f32_16x16x32_bf16(af[0], bfrag, acc[0][ni], 0, 0, 0);
            acc[1][ni] = __builtin_amdgcn_mfma_f32_16x16x32_bf16(af[1], bfrag, acc[1][ni], 0, 0, 0);
        }
    }
    #pragma unroll
    for (int mi = 0; mi < 2; ++mi)
        #pragma unroll
        for (int r = 0; r < 4; ++r) {
            const int row = m0 + w * 32 + mi * 16 + g * 4 + r;
            #pragma unroll
            for (int ni = 0; ni < 8; ++ni) {
                const int f = n0 + ni * 16 + c;
                out[(size_t)row * HDIM + f] = acc[mi][ni][r] + bo[f];
            }
        }
}

extern "C" void kernel_launch(void* const* d_in, const int* in_sizes, int n_in,
                              void* d_out, int out_size, void* d_ws, size_t ws_size,
                              hipStream_t stream) {
    const float* hidden = (const float*)d_in[0];
    // d_in[1] = mask (causality computed analytically)
    const float* past_key = (const float*)d_in[2];
    const float* past_value = (const float*)d_in[3];
    const float* Wq = (const float*)d_in[4];
    const float* bq = (const float*)d_in[5];
    const float* Wk = (const float*)d_in[6];
    const float* bk = (const float*)d_in[7];
    const float* Wv = (const float*)d_in[8];
    const float* bv = (const float*)d_in[9];
    const float* Wo = (const float*)d_in[10];
    const float* bo = (const float*)d_in[11];

    float* out0 = (float*)d_out;
    float* outK = out0 + (size_t)NB * SEQ * HDIM;
    float* outV = outK + (size_t)NB * NHEADS * STOT * HDHEAD;

    char* ws = (char*)d_ws;
    float* cosT = (float*)(ws + OFF_COS);
    float* sinT = (float*)(ws + OFF_SIN);
    unsigned short* hsb = (unsigned short*)(ws + OFF_HSB);
    unsigned short* WT = (unsigned short*)(ws + OFF_WT);
    unsigned short* qbf = (unsigned short*)(ws + OFF_QBF);
    unsigned short* Kc2 = (unsigned short*)(ws + OFF_KC);
    unsigned short* Vt2 = (unsigned short*)(ws + OFF_VT);
    unsigned short* attnb = (unsigned short*)(ws + OFF_ATT);

    k_rope_table<<<dim3(256), dim3(256), 0, stream>>>(cosT, sinT);
    k_cvt_hidden<<<dim3(4096), dim3(256), 0, stream>>>(hidden, hsb);
    k_wt<<<dim3(64, 64, 4), dim3(32, 8), 0, stream>>>(Wq, Wk, Wv, Wo, WT);
    k_pastk<<<dim3(4096), dim3(256), 0, stream>>>(past_key, outK, Kc2);
    k_pastv<<<dim3(16, 2, 32), dim3(64, 4), 0, stream>>>(past_value, outV, Vt2);
    k_gemm_qkv<<<dim3(16, 16, 3), dim3(256), 0, stream>>>(
        hsb, WT, bq, bk, bv, cosT, sinT, qbf, Kc2, Vt2, outK, outV);
    k_attn<<<dim3(16, 32), dim3(256), 0, stream>>>(qbf, Kc2, Vt2, attnb);
    k_gemm_out<<<dim3(16, 16), dim3(256), 0, stream>>>(
        attnb, WT + (size_t)3 * HDIM * HDIM, bo, out0);
}